// Round 2
// baseline (1160.693 us; speedup 1.0000x reference)
//
#include <hip/hip_runtime.h>

// LocalConvolution: out[b,o,i,j] = sum_{c,u,v} x[b,c,i+u,j+v] * w[i,j,o,c,u,v]
// x: [64,64,32,32] f32 (16 MB, L3-resident) ; w: [28,28,128,64,5,5] f32 (642 MB,
// streamed exactly once) ; out: [64,128,28,28] f32 (26 MB).
// Per-position GEMM M=64(b), N=128(o), K=1600, bf16 MFMA 16x16x32.
//
// Round-5: round-4 was latency-bound (404 us @ 1166 GB/s, MfmaUtil 2%,
// VALUBusy 8% -> ~270 us of stall). Cause: every chunk issued its 26 global
// loads and consumed them immediately -> full HBM latency exposed per chunk,
// waves convoy on the per-chunk barrier. This round:
//   - 1-deep register software pipeline on BOTH streams: chunk cb+1's weights
//     (WReg, 10 dwordx4) and x rows (XReg, 8x{dwordx4+dword}) are issued in
//     iteration cb and consumed in cb+1. Named ping-pong sets (xA/xB, wA/wB)
//     keep all register indexing static.
//   - Weights f2bf'd at iteration TOP (data landed during prior MFMA phase):
//     frees the f32 regs before the next prefetch, and the MFMA phase becomes
//     pure ds_read_b128 + MFMA.
//   - A-tile leading dim 160 -> 168 u16 (pad 16 B): MFMA-phase ds_read_b128
//     drops from 8-way to 2-way bank conflict (2-way is free).
//   - Exact-j x loads via 4B-aligned dwordx4 (no DJ template).
// Iteration: [cvtW | writeA | issue cb+1 loads] -> barrier -> [20 ds_read+MFMA].
// Single barrier per chunk is safe with the double-buffered A-tile.

typedef __attribute__((ext_vector_type(8))) short bf16x8;
typedef __attribute__((ext_vector_type(4))) float f32x4;
typedef unsigned int u32;
typedef unsigned short u16;

__device__ __forceinline__ u16 f2bf(float f) {
    u32 u = __float_as_uint(f);
    u = (u + 0x7fffu + ((u >> 16) & 1u)) >> 16;   // RNE
    return (u16)u;
}

__device__ __forceinline__ f32x4 load4u(const float* p) {   // 4B-aligned dwordx4
    f32x4 v; __builtin_memcpy(&v, p, 16); return v;
}

constexpr int KC  = 160;   // k-elements per chunk (5 MFMA k-steps; multiple of 5)
constexpr int LDK = 168;   // padded LDS leading dim (336 B row stride)

struct XReg { f32x4 a[8]; float b[8]; };   // 8 patch rows: floats j..j+4
struct WReg { f32x4 w[10]; };              // 160 B of this thread's weight row

__global__ __launch_bounds__(256, 3) void lconv_fused(const float* __restrict__ x,
                                                      const float* __restrict__ wgt,
                                                      float* __restrict__ out) {
    __shared__ u16 As[2][64 * LDK];        // 2 x 21504 B = 43008 B

    const int bx = blockIdx.x;
    // s-pair (o-halves of same g) and g-neighbors land on the same XCD:
    const int s  = (bx >> 3) & 1;          // o-half
    const int bq = (bx & 7) | ((bx >> 4) << 3);
    const int g  = (bq & 7) * 98 + (bq >> 3);   // XCD swizzle over positions
    const int i = g / 28, j = g - i * 28;

    const int t = threadIdx.x, lane = t & 63, wv = t >> 6;
    const int l15 = lane & 15, quad = lane >> 4;
    const int tb = t >> 2, q = t & 3;      // build role: (batch, quarter)

    const float* xb = x + tb * 65536 + i * 32 + j;
    const int o = s * 64 + wv * 16 + l15;
    const float* wrow = wgt + (size_t)g * 204800 + (size_t)o * 1600 + quad * 8;
    float* outp = out + (size_t)o * 784 + g;

    // ---- pipeline stage helpers (all register indexing static via unroll) ----
    auto loadX = [&](int cb, XReg& r) {
#pragma unroll
        for (int rw = 0; rw < 8; ++rw) {
            const int R = cb * 32 + q * 8 + rw;     // patch row index
            const int c = R / 5, u = R - 5 * c;
            const float* p = xb + c * 1024 + u * 32;
            r.a[rw] = load4u(p);
            r.b[rw] = p[4];
        }
    };
    auto loadW = [&](int cb, WReg& r) {
        const float* wc = wrow + cb * 160;
#pragma unroll
        for (int ks = 0; ks < 5; ++ks) {
            r.w[2 * ks]     = *(const f32x4*)(wc + ks * 32);
            r.w[2 * ks + 1] = *(const f32x4*)(wc + ks * 32 + 4);
        }
    };
    auto cvtW = [&](const WReg& r, bf16x8* bw) {
#pragma unroll
        for (int ks = 0; ks < 5; ++ks) {
            const f32x4 w0 = r.w[2 * ks], w1 = r.w[2 * ks + 1];
            bf16x8 bv;
            bv[0] = (short)f2bf(w0[0]); bv[1] = (short)f2bf(w0[1]);
            bv[2] = (short)f2bf(w0[2]); bv[3] = (short)f2bf(w0[3]);
            bv[4] = (short)f2bf(w1[0]); bv[5] = (short)f2bf(w1[1]);
            bv[6] = (short)f2bf(w1[2]); bv[7] = (short)f2bf(w1[3]);
            bw[ks] = bv;
        }
    };
    auto writeA = [&](const XReg& r, u16* dstbuf) {
        u16 bu[40];
#pragma unroll
        for (int rw = 0; rw < 8; ++rw) {
#pragma unroll
            for (int v = 0; v < 4; ++v) bu[rw * 5 + v] = f2bf(r.a[rw][v]);
            bu[rw * 5 + 4] = f2bf(r.b[rw]);
        }
        u16* dst = dstbuf + tb * LDK + q * 40;
#pragma unroll
        for (int e = 0; e < 5; ++e)
            *(uint4*)(dst + e * 8) = *(const uint4*)&bu[e * 8];
    };

    f32x4 acc[4];
#pragma unroll
    for (int mt = 0; mt < 4; ++mt) acc[mt] = (f32x4)0.f;

    auto mfmaPhase = [&](const u16* A, const bf16x8* bw) {
#pragma unroll
        for (int ks = 0; ks < 5; ++ks)
#pragma unroll
            for (int mt = 0; mt < 4; ++mt) {
                bf16x8 av = *(const bf16x8*)&A[(mt * 16 + l15) * LDK + ks * 32 + quad * 8];
                acc[mt] = __builtin_amdgcn_mfma_f32_16x16x32_bf16(av, bw[ks], acc[mt], 0, 0, 0);
            }
    };

    // ---- software-pipelined main loop: 10 chunks, 2 per p-iteration ----
    XReg xA, xB; WReg wA, wB; bf16x8 bw[5];
    loadW(0, wA); loadX(0, xA);

    for (int p = 0; p < 5; ++p) {
        const int cb = 2 * p;
        // even chunk: consume A-set, prefetch B-set
        cvtW(wA, bw);                       // waits wA (issued last iter)
        writeA(xA, As[0]);                  // waits xA, f2bf, ds_write
        loadW(cb + 1, wB); loadX(cb + 1, xB);
        __syncthreads();
        mfmaPhase(As[0], bw);               // pure LDS + MFMA

        // odd chunk: consume B-set, prefetch A-set
        cvtW(wB, bw);
        writeA(xB, As[1]);
        if (p < 4) { loadW(cb + 2, wA); loadX(cb + 2, xA); }
        __syncthreads();
        mfmaPhase(As[1], bw);
    }

    // ---- epilogue: D[m=quad*4+r][n=l15] -> out[b][o][g], plain stores ----
#pragma unroll
    for (int mt = 0; mt < 4; ++mt)
#pragma unroll
        for (int r = 0; r < 4; ++r) {
            const int b = mt * 16 + quad * 4 + r;
            outp[(size_t)b * 100352] = acc[mt][r];   // 100352 = 128*784
        }
}

extern "C" void kernel_launch(void* const* d_in, const int* in_sizes, int n_in,
                              void* d_out, int out_size, void* d_ws, size_t ws_size,
                              hipStream_t stream) {
    const float* x   = (const float*)d_in[0];
    const float* wgt = (const float*)d_in[1];
    float* out       = (float*)d_out;
    (void)d_ws; (void)ws_size;
    lconv_fused<<<1568, 256, 0, stream>>>(x, wgt, out);
}